// Round 1
// 307.539 us; speedup vs baseline: 1.0102x; 1.0102x over previous
//
#include <hip/hip_runtime.h>

typedef unsigned short u16;
typedef _Float16 f16;
typedef __attribute__((ext_vector_type(8))) short v8s;
typedef __attribute__((ext_vector_type(4))) short v4s;
typedef __attribute__((ext_vector_type(8))) f16   v8h;
typedef __attribute__((ext_vector_type(4))) float v4f;
typedef __attribute__((ext_vector_type(2))) unsigned v2u;

#define NB   8
#define NC   256
#define DQK  32
#define NPIX 4096

__device__ __forceinline__ u16 f2bf(float f) {
  unsigned u = __builtin_bit_cast(unsigned, f);
  u += 0x7FFFu + ((u >> 16) & 1u);   // RNE
  return (u16)(u >> 16);
}
__device__ __forceinline__ u16 f2h(float f) {
  return __builtin_bit_cast(u16, (f16)f);   // v_cvt_f16_f32, RNE
}
__device__ __forceinline__ unsigned cvt_pk_bf16(float lo, float hi) {
  unsigned r;
  asm("v_cvt_pk_bf16_f32 %0, %1, %2" : "=v"(r) : "v"(lo), "v"(hi));
  return r;
}

// ---- W -> fp16 (layouts already [o][c] row-major, elementwise convert) ----
__global__ __launch_bounds__(256)
void convert_w(const float* __restrict__ Wq, const float* __restrict__ Wk,
               const float* __restrict__ Wv,
               u16* __restrict__ Whq, u16* __restrict__ Whk, u16* __restrict__ Whv) {
  int i = blockIdx.x * 256 + threadIdx.x;   // 0..81919
  if (i < 8192)       Whq[i]         = f2h(Wq[i]);
  else if (i < 16384) Whk[i - 8192]  = f2h(Wk[i - 8192]);
  else                Whv[i - 16384] = f2h(Wv[i - 16384]);
}

// ---- x,y fp32 [b][c][n] -> fp16 [b][n][c] (B-frag-friendly pixel-major) ----
__global__ __launch_bounds__(256)
void xpose(const float* __restrict__ x, const float* __restrict__ y,
           u16* __restrict__ xt, u16* __restrict__ yt) {
  const float* __restrict__ src = blockIdx.y ? y : x;
  u16* __restrict__ dst         = blockIdx.y ? yt : xt;
  const int bid = blockIdx.x;              // 0..2047
  const int b  = bid >> 8;
  const int c0 = ((bid >> 6) & 3) * 64;
  const int n0 = (bid & 63) * 64;
  __shared__ u16 T[64][66];                // stride 66: phase-2 reads ~2-way only
  const int t = threadIdx.x, nl = t & 63, cq = t >> 6;
  const float* __restrict__ s = src + ((size_t)b << 20) + (size_t)c0 * NPIX + n0;
#pragma unroll
  for (int i = 0; i < 16; ++i) {
    int c = cq * 16 + i;
    T[c][nl] = f2h(s[(size_t)c * NPIX + nl]);    // coalesced fp32 reads
  }
  __syncthreads();
  u16* __restrict__ d = dst + ((size_t)b << 20) + (size_t)n0 * NC + c0;
#pragma unroll
  for (int i = 0; i < 2; ++i) {
    int nr = (t >> 3) + 32 * i, c8 = (t & 7) * 8;
    v8s v;
#pragma unroll
    for (int j = 0; j < 8; ++j) v[j] = (short)T[c8 + j][nr];
    *(v8s*)(d + (size_t)nr * NC + c8) = v;       // coalesced 16B fp16 writes
  }
}

// ---- All three projections as one MFMA GEMM ----
__global__ __launch_bounds__(256)
void proj_mfma(const u16* __restrict__ xt, const u16* __restrict__ yt,
               const u16* __restrict__ Whq, const float* __restrict__ bq,
               const u16* __restrict__ Whk, const float* __restrict__ bk,
               const u16* __restrict__ Whv, const float* __restrict__ bv,
               u16* __restrict__ Qb, u16* __restrict__ Kb, u16* __restrict__ Vt) {
  const int tid = threadIdx.x, w = tid >> 6, lane = tid & 63;
  const int lr = lane & 15, quad = lane >> 4;
  const int b = blockIdx.x & 7;                    // XCD-affine batch
  const int n0 = (blockIdx.x >> 3) * 64;
  const int n = n0 + w * 16 + lr;
  const size_t bn = ((size_t)b << 12) + n;

  v8h xb[8], yb[8];
  const u16* xp = xt + bn * NC + quad * 8;
  const u16* yp = yt + bn * NC + quad * 8;
#pragma unroll
  for (int t = 0; t < 8; ++t) {
    xb[t] = *(const v8h*)(xp + 32 * t);
    yb[t] = *(const v8h*)(yp + 32 * t);
  }

  // Q and K (2 o-tiles each)
#pragma unroll
  for (int ot = 0; ot < 2; ++ot) {
    v4f aq = {0.f, 0.f, 0.f, 0.f}, ak = {0.f, 0.f, 0.f, 0.f};
#pragma unroll
    for (int t = 0; t < 8; ++t) {
      v8h wq = *(const v8h*)(Whq + (ot * 16 + lr) * 256 + quad * 8 + 32 * t);
      v8h wk = *(const v8h*)(Whk + (ot * 16 + lr) * 256 + quad * 8 + 32 * t);
      aq = __builtin_amdgcn_mfma_f32_16x16x32_f16(wq, xb[t], aq, 0, 0, 0);
      ak = __builtin_amdgcn_mfma_f32_16x16x32_f16(wk, yb[t], ak, 0, 0, 0);
    }
    v4f bqv = *(const v4f*)(bq + ot * 16 + quad * 4);
    v4f bkv = *(const v4f*)(bk + ot * 16 + quad * 4);
    v4s q4, k4;
#pragma unroll
    for (int r = 0; r < 4; ++r) {
      q4[r] = (short)f2h(aq[r] + bqv[r]);
      k4[r] = (short)f2h(ak[r] + bkv[r]);
    }
    *(v4s*)(Qb + bn * DQK + ot * 16 + quad * 4) = q4;   // pixel-major [n][32]
    *(v4s*)(Kb + bn * DQK + ot * 16 + quad * 4) = k4;
  }

  // V (16 o-tiles) -> channel-major bf16 [b][o][n]
  for (int vt = 0; vt < 16; ++vt) {
    v4f av = {0.f, 0.f, 0.f, 0.f};
#pragma unroll
    for (int t = 0; t < 8; ++t) {
      v8h wv = *(const v8h*)(Whv + (vt * 16 + lr) * 256 + quad * 8 + 32 * t);
      av = __builtin_amdgcn_mfma_f32_16x16x32_f16(wv, yb[t], av, 0, 0, 0);
    }
#pragma unroll
    for (int r = 0; r < 4; ++r) {
      int o = vt * 16 + quad * 4 + r;
      Vt[(((size_t)b << 8) + o) * NPIX + n] = f2bf(av[r] + bv[o]);
    }
  }
}

// ---- Fused attention, 8-wave blocks for occupancy ----
// Wave w = (qt = w&3, h = w>>2): S for q-subtile qt x kv-half h (2 MFMAs),
// PV for its own 32-channel slice (acc[4][2]).  S computed SWAPPED
// (A=K, B=Q) so each lane holds 4 consecutive-kv P values -> packed bf16
// store via v_cvt_pk + ds_write_b64.  Row-sum l accumulated in f32 regs.
// One barrier per kv-step (double-buffered Ps).  K/V prefetch 1 step ahead.
__global__ __launch_bounds__(512, 4)
void attn_kernel(const u16* __restrict__ Qb, const u16* __restrict__ Kb,
                 const u16* __restrict__ Vt, float* __restrict__ out) {
  __shared__ __attribute__((aligned(16))) u16 Ps[2][4][16 * 72];
  __shared__ float Ls[2][64];

  const int tid  = threadIdx.x;
  const int w    = tid >> 6;      // 0..7
  const int lane = tid & 63;
  const int lr   = lane & 15;
  const int quad = lane >> 4;
  const int qt   = w & 3;         // S q-subtile owned by this wave
  const int h    = w >> 2;        // S kv-half owned by this wave

  const int b  = blockIdx.x & 7;            // XCD-affine batch mapping
  const int q0 = (blockIdx.x >> 3) << 6;

  const u16* Qp = Qb + ((size_t)b * NPIX + q0) * DQK;
  const u16* Kp = Kb + (size_t)b * NPIX * DQK + (size_t)(h * 32 + lr) * DQK + quad * 8;
  const u16* Vp = Vt + (size_t)b * NC * NPIX + (size_t)(w * 32 + lr) * NPIX + quad * 8;

  // Q as B-operand: lane holds col q = qt*16+lr, k = quad*8+j
  v8h q_frag = *(const v8h*)(Qp + (qt * 16 + lr) * DQK + quad * 8);

  v4f acc[4][2];
#pragma unroll
  for (int q2 = 0; q2 < 4; ++q2)
#pragma unroll
    for (int ct = 0; ct < 2; ++ct) acc[q2][ct] = (v4f){0.f, 0.f, 0.f, 0.f};
  float lsum = 0.f;

  // prologue loads for kv0 = 0
  v8h kf[2];
  v8s vf[2][2];
#pragma unroll
  for (int nt = 0; nt < 2; ++nt)
    kf[nt] = *(const v8h*)(Kp + (size_t)(nt * 16) * DQK);
#pragma unroll
  for (int ct = 0; ct < 2; ++ct) {
    const u16* vs = Vp + (size_t)(ct * 16) * NPIX;
    vf[ct][0] = *(const v8s*)(vs);
    vf[ct][1] = *(const v8s*)(vs + 32);
  }

#pragma unroll 2
  for (int it = 0; it < 64; ++it) {
    const int kv0 = it * 64;
    const int buf = it & 1;
    // S^T tiles: A = K rows (kv), B = Q cols (q).  D: col=lr=q, row=quad*4+r=kv
    v4f s[2];
#pragma unroll
    for (int nt = 0; nt < 2; ++nt)
      s[nt] = __builtin_amdgcn_mfma_f32_16x16x32_f16(kf[nt], q_frag,
                                                     (v4f){0.f, 0.f, 0.f, 0.f}, 0, 0, 0);
    // prefetch next step's K and V while exp/LDS/PV run
    v8h kn[2];
    v8s vn[2][2];
    if (it < 63) {
      const int kvn = kv0 + 64;
#pragma unroll
      for (int nt = 0; nt < 2; ++nt)
        kn[nt] = *(const v8h*)(Kp + (size_t)(kvn + nt * 16) * DQK);
#pragma unroll
      for (int ct = 0; ct < 2; ++ct) {
        const u16* vs = Vp + (size_t)(ct * 16) * NPIX + kvn;
        vn[ct][0] = *(const v8s*)(vs);
        vn[ct][1] = *(const v8s*)(vs + 32);
      }
    }
    // p = exp2(s*log2e - 48): fixed shift, bf16 keeps the tail.
    // 4 consecutive kv per lane -> 2 cvt_pk + 1 ds_write_b64 per s-tile.
#pragma unroll
    for (int nt = 0; nt < 2; ++nt) {
      float p0 = exp2f(fmaf(s[nt][0], 1.44269504f, -48.0f));
      float p1 = exp2f(fmaf(s[nt][1], 1.44269504f, -48.0f));
      float p2 = exp2f(fmaf(s[nt][2], 1.44269504f, -48.0f));
      float p3 = exp2f(fmaf(s[nt][3], 1.44269504f, -48.0f));
      lsum += (p0 + p1) + (p2 + p3);      // exact f32 row-sum partial (q = lr)
      v2u pk;
      pk[0] = cvt_pk_bf16(p0, p1);
      pk[1] = cvt_pk_bf16(p2, p3);
      *(v2u*)(&Ps[buf][qt][lr * 72 + h * 32 + nt * 16 + quad * 4]) = pk;
    }
    __syncthreads();   // Ps[buf] ready; prior buffer's readers already past last sync
    // O^T += V * P^T for all 4 q-subtiles, own 32-ch slice
    __builtin_amdgcn_s_setprio(1);
#pragma unroll
    for (int q2 = 0; q2 < 4; ++q2) {
      v8s p0 = *(const v8s*)(&Ps[buf][q2][lr * 72 + quad * 8]);
      v8s p1 = *(const v8s*)(&Ps[buf][q2][lr * 72 + 32 + quad * 8]);
#pragma unroll
      for (int ct = 0; ct < 2; ++ct) {
        acc[q2][ct] = __builtin_amdgcn_mfma_f32_16x16x32_bf16(vf[ct][0], p0, acc[q2][ct], 0, 0, 0);
        acc[q2][ct] = __builtin_amdgcn_mfma_f32_16x16x32_bf16(vf[ct][1], p1, acc[q2][ct], 0, 0, 0);
      }
    }
    __builtin_amdgcn_s_setprio(0);
#pragma unroll
    for (int nt = 0; nt < 2; ++nt) kf[nt] = kn[nt];
#pragma unroll
    for (int ct = 0; ct < 2; ++ct) { vf[ct][0] = vn[ct][0]; vf[ct][1] = vn[ct][1]; }
  }

  // l: reduce lane partials across quads (same q = lr in all 4 quads)
  lsum += __shfl_xor(lsum, 16);
  lsum += __shfl_xor(lsum, 32);
  if (quad == 0) Ls[h][qt * 16 + lr] = lsum;   // unique (h,qt) slot per wave
  __syncthreads();
  float linv[4];
#pragma unroll
  for (int q2 = 0; q2 < 4; ++q2)
    linv[q2] = 1.0f / (Ls[0][q2 * 16 + lr] + Ls[1][q2 * 16 + lr]);

  float* op = out + ((size_t)b * NC + w * 32) * NPIX + q0;
#pragma unroll
  for (int ct = 0; ct < 2; ++ct)
#pragma unroll
    for (int r = 0; r < 4; ++r) {
      float* orow = op + (size_t)(ct * 16 + quad * 4 + r) * NPIX;
#pragma unroll
      for (int q2 = 0; q2 < 4; ++q2)
        orow[q2 * 16 + lr] = acc[q2][ct][r] * linv[q2];
    }
}

extern "C" void kernel_launch(void* const* d_in, const int* in_sizes, int n_in,
                              void* d_out, int out_size, void* d_ws, size_t ws_size,
                              hipStream_t stream) {
  const float* x  = (const float*)d_in[0];
  const float* y  = (const float*)d_in[1];
  const float* Wq = (const float*)d_in[2];
  const float* bq = (const float*)d_in[3];
  const float* Wk = (const float*)d_in[4];
  const float* bk = (const float*)d_in[5];
  const float* Wv = (const float*)d_in[6];
  const float* bv = (const float*)d_in[7];
  float* out = (float*)d_out;

  // ws: Qb 2MB | Kb 2MB | Vt 16MB | xt 16MB | yt 16MB | Whq/Whk/Whv 160KB  ~= 54.6MB
  u16* Qb  = (u16*)d_ws;
  u16* Kb  = Qb + (size_t)NB * NPIX * DQK;
  u16* Vt  = Kb + (size_t)NB * NPIX * DQK;
  u16* xt  = Vt + (size_t)NB * NC * NPIX;
  u16* yt  = xt + (size_t)NB * NPIX * NC;
  u16* Whq = yt + (size_t)NB * NPIX * NC;
  u16* Whk = Whq + 32 * 256;
  u16* Whv = Whk + 32 * 256;

  hipLaunchKernelGGL(convert_w, dim3(320), dim3(256), 0, stream, Wq, Wk, Wv, Whq, Whk, Whv);
  hipLaunchKernelGGL(xpose, dim3(2048, 2), dim3(256), 0, stream, x, y, xt, yt);
  hipLaunchKernelGGL(proj_mfma, dim3(512), dim3(256), 0, stream,
                     xt, yt, Whq, bq, Whk, bk, Whv, bv, Qb, Kb, Vt);
  hipLaunchKernelGGL(attn_kernel, dim3(512), dim3(512), 0, stream, Qb, Kb, Vt, out);
}